// Round 1
// baseline (2152.993 us; speedup 1.0000x reference)
//
#include <hip/hip_runtime.h>
#include <hip/hip_bf16.h>
#include <math.h>

#define F 128
#define H 256
#define C 40
#define KHOPS 10
#define TM 64
#define HK 64

// ---------------- CSR build ----------------
__global__ void k_count(const int* __restrict__ dst, int E, int* __restrict__ cnt) {
    int e = blockIdx.x * 256 + threadIdx.x;
    if (e < E) atomicAdd(&cnt[dst[e]], 1);
}

__global__ void k_scan1(const int* __restrict__ cnt, int n, int* __restrict__ bsum) {
    __shared__ int sh[256];
    int t = threadIdx.x;
    int base = blockIdx.x * 4096 + t * 16;
    int s = 0;
    for (int i = 0; i < 16; i++) { int idx = base + i; if (idx < n) s += cnt[idx]; }
    sh[t] = s; __syncthreads();
    for (int o = 128; o > 0; o >>= 1) {
        if (t < o) sh[t] += sh[t + o];
        __syncthreads();
    }
    if (t == 0) bsum[blockIdx.x] = sh[0];
}

__global__ void k_scan2(int* __restrict__ bsum, int nb) {
    if (threadIdx.x == 0) {
        int acc = 0;
        for (int i = 0; i < nb; i++) { int v = bsum[i]; bsum[i] = acc; acc += v; }
    }
}

__global__ void k_scan3(const int* __restrict__ cnt, int n, const int* __restrict__ bsum,
                        int* __restrict__ rp) {
    __shared__ int sh[256];
    int t = threadIdx.x;
    int base = blockIdx.x * 4096 + t * 16;
    int local[16]; int s = 0;
    for (int i = 0; i < 16; i++) {
        int idx = base + i;
        int v = (idx < n) ? cnt[idx] : 0;
        local[i] = v; s += v;
    }
    sh[t] = s; __syncthreads();
    for (int o = 1; o < 256; o <<= 1) {
        int v = (t >= o) ? sh[t - o] : 0;
        __syncthreads();
        sh[t] += v;
        __syncthreads();
    }
    int excl = (t == 0) ? 0 : sh[t - 1];
    int run = bsum[blockIdx.x] + excl;
    for (int i = 0; i < 16; i++) {
        int idx = base + i;
        if (idx < n) { rp[idx] = run; run += local[i]; }
    }
}

__global__ void k_fill(const int* __restrict__ src, const int* __restrict__ dst,
                       const float* __restrict__ nrm, int E, const int* __restrict__ rp,
                       int* __restrict__ cur, int* __restrict__ es, float* __restrict__ en) {
    int e = blockIdx.x * 256 + threadIdx.x;
    if (e < E) {
        int d = dst[e];
        int p = rp[d] + atomicAdd(&cur[d], 1);
        es[p] = src[e];
        en[p] = nrm[e];
    }
}

// ---------------- fused MLP: Linear(128->256)+BN+ReLU+Linear(256->40) ----------------
__launch_bounds__(256, 1)
__global__ void k_mlp(const float* __restrict__ x, const float* __restrict__ W1,
                      const float* __restrict__ b1, const float* __restrict__ g,
                      const float* __restrict__ be, const float* __restrict__ mu,
                      const float* __restrict__ var, const float* __restrict__ W2,
                      const float* __restrict__ b2, float* __restrict__ h, int N) {
    __shared__ float xs[F][68];    // [f][node] transposed, pad 68 (b128-aligned rows)
    __shared__ float w1s[F][HK];   // [f][hh]
    __shared__ float h1s[TM][68];  // [node][hh] pad 68
    __shared__ float w2s[C][68];   // [c][hh] transposed, pad 68
    __shared__ float asc[HK], dsc[HK];

    int t = threadIdx.x;
    int n0 = blockIdx.x * TM;

    // stage x tile (transposed into LDS)
    for (int k = 0; k < 8; k++) {
        int idx = k * 256 + t;          // over 2048 float4
        int node = idx >> 5, f4 = idx & 31;
        int n = n0 + node;
        float4 v = (n < N) ? ((const float4*)x)[(size_t)n * (F / 4) + f4]
                           : make_float4(0.f, 0.f, 0.f, 0.f);
        xs[f4 * 4 + 0][node] = v.x;
        xs[f4 * 4 + 1][node] = v.y;
        xs[f4 * 4 + 2][node] = v.z;
        xs[f4 * 4 + 3][node] = v.w;
    }

    float acc2[10];
    {
        int cg = t & 3;
        #pragma unroll
        for (int j = 0; j < 10; j++) acc2[j] = b2[cg * 10 + j];
    }

    int tn = t & 15, th = t >> 4;       // stage-1 tiling: 4 nodes x 4 hh per thread

    for (int h0 = 0; h0 < H; h0 += HK) {
        // load W1 chunk
        for (int k = 0; k < 8; k++) {
            int idx4 = k * 256 + t;     // over 2048 float4
            int f = idx4 >> 4, h4 = idx4 & 15;
            float4 v = ((const float4*)W1)[(size_t)f * (H / 4) + (h0 >> 2) + h4];
            *((float4*)&w1s[f][h4 * 4]) = v;
        }
        // load W2 chunk transposed
        for (int k = 0; k < 10; k++) {
            int idx = k * 256 + t;      // over 2560
            int hh = idx / 40, c = idx % 40;
            w2s[c][hh] = W2[(size_t)(h0 + hh) * C + c];
        }
        // fused BN scale/shift (includes b1)
        if (t < HK) {
            int hg = h0 + t;
            float a = g[hg] * rsqrtf(var[hg] + 1e-5f);
            asc[t] = a;
            dsc[t] = (b1[hg] - mu[hg]) * a + be[hg];
        }
        __syncthreads();

        // stage 1: x @ W1 chunk
        float acc[4][4];
        #pragma unroll
        for (int i = 0; i < 4; i++)
            #pragma unroll
            for (int j = 0; j < 4; j++) acc[i][j] = 0.f;

        #pragma unroll 4
        for (int f = 0; f < F; f++) {
            float4 xv = *((const float4*)&xs[f][tn * 4]);
            float4 wv = *((const float4*)&w1s[f][th * 4]);
            float xa[4] = {xv.x, xv.y, xv.z, xv.w};
            float wa[4] = {wv.x, wv.y, wv.z, wv.w};
            #pragma unroll
            for (int i = 0; i < 4; i++)
                #pragma unroll
                for (int j = 0; j < 4; j++) acc[i][j] += xa[i] * wa[j];
        }
        // BN + ReLU -> h1s
        #pragma unroll
        for (int i = 0; i < 4; i++) {
            float4 o;
            float* po = (float*)&o;
            #pragma unroll
            for (int j = 0; j < 4; j++) {
                int hh = th * 4 + j;
                float v = acc[i][j] * asc[hh] + dsc[hh];
                po[j] = v > 0.f ? v : 0.f;
            }
            *((float4*)&h1s[tn * 4 + i][th * 4]) = o;
        }
        __syncthreads();

        // stage 2: h1 chunk @ W2 chunk
        int n_loc = t >> 2, cg = t & 3;
        #pragma unroll 4
        for (int hh = 0; hh < HK; hh += 4) {
            float4 hv = *((const float4*)&h1s[n_loc][hh]);
            #pragma unroll
            for (int j = 0; j < 10; j++) {
                float4 w4 = *((const float4*)&w2s[cg * 10 + j][hh]);
                acc2[j] += hv.x * w4.x + hv.y * w4.y + hv.z * w4.z + hv.w * w4.w;
            }
        }
        __syncthreads();
    }

    int n_loc = t >> 2, cg = t & 3;
    int n = n0 + n_loc;
    if (n < N) {
        #pragma unroll
        for (int j = 0; j < 10; j++) h[(size_t)n * C + cg * 10 + j] = acc2[j];
    }
}

// ---------------- combine for snapshot 0 ----------------
__global__ void k_comb0(const float* __restrict__ hbuf, float* __restrict__ oacc,
                        const float* __restrict__ pw, const float* __restrict__ pb, int N) {
    __shared__ float red[320];
    __shared__ float sig[8];
    int t = threadIdx.x;
    int nl = t / 40, c = t % 40;
    int n = blockIdx.x * 8 + nl;
    float v = (n < N) ? hbuf[(size_t)n * C + c] : 0.f;
    red[t] = v * pw[c];
    __syncthreads();
    if (c == 0) {
        float s = 0.f;
        for (int q = 0; q < 40; q++) s += red[nl * 40 + q];
        sig[nl] = 1.f / (1.f + expf(-(s + pb[0])));
    }
    __syncthreads();
    if (n < N) oacc[(size_t)n * C + c] += sig[nl] * v;
}

// ---------------- one propagation hop, fused with retain-combine ----------------
__global__ void k_hop(const float* __restrict__ cur, float* __restrict__ nxt,
                      float* __restrict__ oacc, const int* __restrict__ rp,
                      const int* __restrict__ es, const float* __restrict__ en,
                      const float* __restrict__ pw, const float* __restrict__ pb, int N) {
    __shared__ float red[320];
    __shared__ float sig[8];
    int t = threadIdx.x;
    int nl = t / 40, c = t % 40;
    int n = blockIdx.x * 8 + nl;
    float acc = 0.f;
    if (n < N) {
        int b = rp[n], e = rp[n + 1];
        for (int j = b; j < e; j++) {
            acc += en[j] * cur[(size_t)es[j] * C + c];
        }
        nxt[(size_t)n * C + c] = acc;
    }
    red[t] = (n < N) ? acc * pw[c] : 0.f;
    __syncthreads();
    if (c == 0) {
        float s = 0.f;
        for (int q = 0; q < 40; q++) s += red[nl * 40 + q];
        sig[nl] = 1.f / (1.f + expf(-(s + pb[0])));
    }
    __syncthreads();
    if (n < N) oacc[(size_t)n * C + c] += sig[nl] * acc;
}

// ---------------- in-place log_softmax over C ----------------
__global__ void k_lsm(float* __restrict__ io, int N) {
    __shared__ float red[320];
    __shared__ float statm[8];
    __shared__ float stats[8];
    int t = threadIdx.x;
    int nl = t / 40, c = t % 40;
    int n = blockIdx.x * 8 + nl;
    float v = (n < N) ? io[(size_t)n * C + c] : -1e30f;
    red[t] = v;
    __syncthreads();
    if (c == 0) {
        float m = -1e30f;
        for (int q = 0; q < 40; q++) m = fmaxf(m, red[nl * 40 + q]);
        statm[nl] = m;
    }
    __syncthreads();
    float m = statm[nl];
    float ex = expf(v - m);
    red[t] = (n < N) ? ex : 0.f;
    __syncthreads();
    if (c == 0) {
        float s = 0.f;
        for (int q = 0; q < 40; q++) s += red[nl * 40 + q];
        stats[nl] = logf(s);
    }
    __syncthreads();
    if (n < N) io[(size_t)n * C + c] = (v - m) - stats[nl];
}

extern "C" void kernel_launch(void* const* d_in, const int* in_sizes, int n_in,
                              void* d_out, int out_size, void* d_ws, size_t ws_size,
                              hipStream_t stream) {
    const float* x   = (const float*)d_in[0];
    const int*   ei  = (const int*)d_in[1];     // [2,E]: src row then dst row
    const float* nrm = (const float*)d_in[2];
    const float* W1  = (const float*)d_in[3];
    const float* b1  = (const float*)d_in[4];
    const float* g   = (const float*)d_in[5];
    const float* be  = (const float*)d_in[6];
    const float* mu  = (const float*)d_in[7];
    const float* var = (const float*)d_in[8];
    const float* W2  = (const float*)d_in[9];
    const float* b2  = (const float*)d_in[10];
    const float* pw  = (const float*)d_in[11];
    const float* pb  = (const float*)d_in[12];
    float* out = (float*)d_out;

    int N = in_sizes[0] / F;
    int E = in_sizes[2];

    char* w = (char*)d_ws;
    auto alloc = [&](size_t bytes) {
        void* p = (void*)w;
        w += ((bytes + 255) / 256) * 256;
        return p;
    };
    int*   rp     = (int*)alloc((size_t)(N + 1) * 4);
    int*   cursor = (int*)alloc((size_t)(N + 1) * 4);
    int*   bsum   = (int*)alloc(256 * 4);
    int*   es     = (int*)alloc((size_t)E * 4);
    float* en     = (float*)alloc((size_t)E * 4);
    float* bufA   = (float*)alloc((size_t)N * C * 4);
    float* bufB   = (float*)alloc((size_t)N * C * 4);

    hipMemsetAsync(cursor, 0, (size_t)(N + 1) * 4, stream);
    hipMemsetAsync(out, 0, (size_t)N * C * 4, stream);

    k_count<<<(E + 255) / 256, 256, 0, stream>>>(ei + E, E, cursor);

    int n1 = N + 1;
    int NB = (n1 + 4095) / 4096;
    k_scan1<<<NB, 256, 0, stream>>>(cursor, n1, bsum);
    k_scan2<<<1, 64, 0, stream>>>(bsum, NB);
    k_scan3<<<NB, 256, 0, stream>>>(cursor, n1, bsum, rp);

    hipMemsetAsync(cursor, 0, (size_t)(N + 1) * 4, stream);
    k_fill<<<(E + 255) / 256, 256, 0, stream>>>(ei, ei + E, nrm, E, rp, cursor, es, en);

    k_mlp<<<(N + TM - 1) / TM, 256, 0, stream>>>(x, W1, b1, g, be, mu, var, W2, b2, bufA, N);

    int nodeBlocks = (N + 7) / 8;
    k_comb0<<<nodeBlocks, 320, 0, stream>>>(bufA, out, pw, pb, N);

    float* cur = bufA;
    float* nxt = bufB;
    for (int k = 0; k < KHOPS; k++) {
        k_hop<<<nodeBlocks, 320, 0, stream>>>(cur, nxt, out, rp, es, en, pw, pb, N);
        float* tmp = cur; cur = nxt; nxt = tmp;
    }

    k_lsm<<<nodeBlocks, 320, 0, stream>>>(out, N);
}

// Round 2
// 1144.527 us; speedup vs baseline: 1.8811x; 1.8811x over previous
//
#include <hip/hip_runtime.h>
#include <hip/hip_bf16.h>
#include <math.h>

#define F 128
#define H 256
#define C 40
#define KHOPS 10
#define TM 64
#define HK 64

// ---------------- CSR build ----------------
__global__ void k_count(const int* __restrict__ dst, int E, int* __restrict__ cnt) {
    int e = blockIdx.x * 256 + threadIdx.x;
    if (e < E) atomicAdd(&cnt[dst[e]], 1);
}

__global__ void k_scan1(const int* __restrict__ cnt, int n, int* __restrict__ bsum) {
    __shared__ int sh[256];
    int t = threadIdx.x;
    int base = blockIdx.x * 4096 + t * 16;
    int s = 0;
    for (int i = 0; i < 16; i++) { int idx = base + i; if (idx < n) s += cnt[idx]; }
    sh[t] = s; __syncthreads();
    for (int o = 128; o > 0; o >>= 1) {
        if (t < o) sh[t] += sh[t + o];
        __syncthreads();
    }
    if (t == 0) bsum[blockIdx.x] = sh[0];
}

__global__ void k_scan2(int* __restrict__ bsum, int nb) {
    if (threadIdx.x == 0) {
        int acc = 0;
        for (int i = 0; i < nb; i++) { int v = bsum[i]; bsum[i] = acc; acc += v; }
    }
}

__global__ void k_scan3(const int* __restrict__ cnt, int n, const int* __restrict__ bsum,
                        int* __restrict__ rp) {
    __shared__ int sh[256];
    int t = threadIdx.x;
    int base = blockIdx.x * 4096 + t * 16;
    int local[16]; int s = 0;
    for (int i = 0; i < 16; i++) {
        int idx = base + i;
        int v = (idx < n) ? cnt[idx] : 0;
        local[i] = v; s += v;
    }
    sh[t] = s; __syncthreads();
    for (int o = 1; o < 256; o <<= 1) {
        int v = (t >= o) ? sh[t - o] : 0;
        __syncthreads();
        sh[t] += v;
        __syncthreads();
    }
    int excl = (t == 0) ? 0 : sh[t - 1];
    int run = bsum[blockIdx.x] + excl;
    for (int i = 0; i < 16; i++) {
        int idx = base + i;
        if (idx < n) { rp[idx] = run; run += local[i]; }
    }
}

__global__ void k_fill(const int* __restrict__ src, const int* __restrict__ dst,
                       const float* __restrict__ nrm, int E, const int* __restrict__ rp,
                       int* __restrict__ cur, int2* __restrict__ ep) {
    int e = blockIdx.x * 256 + threadIdx.x;
    if (e < E) {
        int d = dst[e];
        int p = rp[d] + atomicAdd(&cur[d], 1);
        ep[p] = make_int2(src[e], __float_as_int(nrm[e]));
    }
}

// ------- fused MLP: Linear(128->256)+BN+ReLU+Linear(256->40) + retain-combine hop0 -------
__launch_bounds__(256, 2)
__global__ void k_mlp(const float* __restrict__ x, const float* __restrict__ W1,
                      const float* __restrict__ b1, const float* __restrict__ g,
                      const float* __restrict__ be, const float* __restrict__ mu,
                      const float* __restrict__ var, const float* __restrict__ W2,
                      const float* __restrict__ b2, const float* __restrict__ pw,
                      const float* __restrict__ pb,
                      float* __restrict__ h, float* __restrict__ oacc, int N) {
    __shared__ float xs[TM][132];   // natural layout [node][f], pad 132 (conflict-free)
    __shared__ float h1s[TM][68];   // [node][hh] pad 68
    __shared__ float w2s[C][68];    // [c][hh] transposed, pad 68
    __shared__ float asc[HK], dsc[HK];
    __shared__ float redc[256];
    __shared__ float sigv[TM];

    int t = threadIdx.x;
    int n0 = blockIdx.x * TM;

    // stage x tile, natural layout, coalesced loads + conflict-free b128 stores
    for (int k = 0; k < 8; k++) {
        int idx = k * 256 + t;          // over 2048 float4
        int node = idx >> 5, f4 = idx & 31;
        int n = n0 + node;
        float4 v = (n < N) ? ((const float4*)x)[(size_t)n * (F / 4) + f4]
                           : make_float4(0.f, 0.f, 0.f, 0.f);
        *((float4*)&xs[node][f4 * 4]) = v;
    }

    float acc2[10];
    {
        int cg = t & 3;
        #pragma unroll
        for (int j = 0; j < 10; j++) acc2[j] = b2[cg * 10 + j];
    }

    int tn = t & 15, th = t >> 4;       // stage-1 tiling: 4 nodes x 4 hh per thread
    const float4* W1g = (const float4*)W1;   // [F][H/4]

    for (int h0 = 0; h0 < H; h0 += HK) {
        // load W2 chunk transposed
        for (int k = 0; k < 10; k++) {
            int idx = k * 256 + t;      // over 2560
            int hh = idx / 40, c = idx % 40;
            w2s[c][hh] = W2[(size_t)(h0 + hh) * C + c];
        }
        // fused BN scale/shift (includes b1)
        if (t < HK) {
            int hg = h0 + t;
            float a = g[hg] * rsqrtf(var[hg] + 1e-5f);
            asc[t] = a;
            dsc[t] = (b1[hg] - mu[hg]) * a + be[hg];
        }
        __syncthreads();

        // stage 1: x @ W1 chunk  (W1 direct from global: 16-lane-broadcast b128, L1/L2-hot)
        float acc[4][4];
        #pragma unroll
        for (int i = 0; i < 4; i++)
            #pragma unroll
            for (int j = 0; j < 4; j++) acc[i][j] = 0.f;

        #pragma unroll 4
        for (int f0 = 0; f0 < F; f0 += 4) {
            float4 wv[4];
            #pragma unroll
            for (int q = 0; q < 4; q++)
                wv[q] = W1g[(size_t)(f0 + q) * (H / 4) + (h0 >> 2) + th];
            float4 xv[4];
            #pragma unroll
            for (int i = 0; i < 4; i++)
                xv[i] = *((const float4*)&xs[tn * 4 + i][f0]);
            #pragma unroll
            for (int i = 0; i < 4; i++) {
                float xa[4] = {xv[i].x, xv[i].y, xv[i].z, xv[i].w};
                #pragma unroll
                for (int q = 0; q < 4; q++) {
                    float wa[4] = {wv[q].x, wv[q].y, wv[q].z, wv[q].w};
                    #pragma unroll
                    for (int j = 0; j < 4; j++) acc[i][j] += xa[q] * wa[j];
                }
            }
        }
        // BN + ReLU -> h1s
        #pragma unroll
        for (int i = 0; i < 4; i++) {
            float4 o;
            float* po = (float*)&o;
            #pragma unroll
            for (int j = 0; j < 4; j++) {
                int hh = th * 4 + j;
                float v = acc[i][j] * asc[hh] + dsc[hh];
                po[j] = v > 0.f ? v : 0.f;
            }
            *((float4*)&h1s[tn * 4 + i][th * 4]) = o;
        }
        __syncthreads();

        // stage 2: h1 chunk @ W2 chunk
        int n_loc = t >> 2, cg = t & 3;
        #pragma unroll 4
        for (int hh = 0; hh < HK; hh += 4) {
            float4 hv = *((const float4*)&h1s[n_loc][hh]);
            #pragma unroll
            for (int j = 0; j < 10; j++) {
                float4 w4 = *((const float4*)&w2s[cg * 10 + j][hh]);
                acc2[j] += hv.x * w4.x + hv.y * w4.y + hv.z * w4.z + hv.w * w4.w;
            }
        }
        __syncthreads();
    }

    // epilogue: write h, fused snapshot-0 retain combine (out = sigmoid(h.pw+pb)*h)
    int n_loc = t >> 2, cg = t & 3;
    int n = n0 + n_loc;
    float part = 0.f;
    #pragma unroll
    for (int j = 0; j < 10; j++) part += acc2[j] * pw[cg * 10 + j];
    redc[t] = part;
    __syncthreads();
    if (cg == 0) {
        float s = redc[n_loc * 4] + redc[n_loc * 4 + 1] + redc[n_loc * 4 + 2] + redc[n_loc * 4 + 3];
        sigv[n_loc] = 1.f / (1.f + expf(-(s + pb[0])));
    }
    __syncthreads();
    if (n < N) {
        float sg = sigv[n_loc];
        #pragma unroll
        for (int j = 0; j < 10; j++) {
            h[(size_t)n * C + cg * 10 + j] = acc2[j];
            oacc[(size_t)n * C + cg * 10 + j] = sg * acc2[j];   // first contribution: store
        }
    }
}

// ---------------- one propagation hop, fused with retain-combine ----------------
// 320 threads: 32 nodes/block, 10 lanes/node, float4 per lane.
__global__ void k_hop(const float4* __restrict__ cur4, float4* __restrict__ nxt4,
                      float4* __restrict__ oacc4, const int* __restrict__ rp,
                      const int2* __restrict__ ep,
                      const float* __restrict__ pw, const float* __restrict__ pb, int N) {
    __shared__ float red[320];
    __shared__ float sig[32];
    int t = threadIdx.x;
    int nl = t / 10, c4 = t % 10;
    int n = blockIdx.x * 32 + nl;
    float4 acc = make_float4(0.f, 0.f, 0.f, 0.f);
    if (n < N) {
        int b = rp[n], e = rp[n + 1];
        int j = b;
        for (; j + 4 <= e; j += 4) {
            int2 e0 = ep[j], e1 = ep[j + 1], e2 = ep[j + 2], e3 = ep[j + 3];
            float4 v0 = cur4[(size_t)e0.x * 10 + c4];
            float4 v1 = cur4[(size_t)e1.x * 10 + c4];
            float4 v2 = cur4[(size_t)e2.x * 10 + c4];
            float4 v3 = cur4[(size_t)e3.x * 10 + c4];
            float w0 = __int_as_float(e0.y), w1 = __int_as_float(e1.y);
            float w2 = __int_as_float(e2.y), w3 = __int_as_float(e3.y);
            acc.x += w0 * v0.x; acc.y += w0 * v0.y; acc.z += w0 * v0.z; acc.w += w0 * v0.w;
            acc.x += w1 * v1.x; acc.y += w1 * v1.y; acc.z += w1 * v1.z; acc.w += w1 * v1.w;
            acc.x += w2 * v2.x; acc.y += w2 * v2.y; acc.z += w2 * v2.z; acc.w += w2 * v2.w;
            acc.x += w3 * v3.x; acc.y += w3 * v3.y; acc.z += w3 * v3.z; acc.w += w3 * v3.w;
        }
        for (; j < e; j++) {
            int2 e0 = ep[j];
            float4 v0 = cur4[(size_t)e0.x * 10 + c4];
            float w0 = __int_as_float(e0.y);
            acc.x += w0 * v0.x; acc.y += w0 * v0.y; acc.z += w0 * v0.z; acc.w += w0 * v0.w;
        }
        nxt4[(size_t)n * 10 + c4] = acc;
    }
    // retain-combine
    float4 pwv = ((const float4*)pw)[c4];
    red[t] = acc.x * pwv.x + acc.y * pwv.y + acc.z * pwv.z + acc.w * pwv.w;
    __syncthreads();
    if (c4 == 0) {
        float s = 0.f;
        #pragma unroll
        for (int q = 0; q < 10; q++) s += red[nl * 10 + q];
        sig[nl] = 1.f / (1.f + expf(-(s + pb[0])));
    }
    __syncthreads();
    if (n < N) {
        float sg = sig[nl];
        float4 o = oacc4[(size_t)n * 10 + c4];
        o.x += sg * acc.x; o.y += sg * acc.y; o.z += sg * acc.z; o.w += sg * acc.w;
        oacc4[(size_t)n * 10 + c4] = o;
    }
}

// ---------------- in-place log_softmax over C (float4) ----------------
__global__ void k_lsm(float4* __restrict__ io, int N) {
    __shared__ float red[320];
    __shared__ float statm[32];
    __shared__ float stats[32];
    int t = threadIdx.x;
    int nl = t / 10, c4 = t % 10;
    int n = blockIdx.x * 32 + nl;
    bool ok = n < N;
    float4 v = ok ? io[(size_t)n * 10 + c4] : make_float4(-1e30f, -1e30f, -1e30f, -1e30f);
    red[t] = fmaxf(fmaxf(v.x, v.y), fmaxf(v.z, v.w));
    __syncthreads();
    if (c4 == 0) {
        float m = -1e30f;
        #pragma unroll
        for (int q = 0; q < 10; q++) m = fmaxf(m, red[nl * 10 + q]);
        statm[nl] = m;
    }
    __syncthreads();
    float m = statm[nl];
    float e0 = expf(v.x - m), e1 = expf(v.y - m), e2 = expf(v.z - m), e3 = expf(v.w - m);
    red[t] = e0 + e1 + e2 + e3;
    __syncthreads();
    if (c4 == 0) {
        float s = 0.f;
        #pragma unroll
        for (int q = 0; q < 10; q++) s += red[nl * 10 + q];
        stats[nl] = logf(s);
    }
    __syncthreads();
    if (ok) {
        float ls = stats[nl];
        io[(size_t)n * 10 + c4] = make_float4(v.x - m - ls, v.y - m - ls, v.z - m - ls, v.w - m - ls);
    }
}

extern "C" void kernel_launch(void* const* d_in, const int* in_sizes, int n_in,
                              void* d_out, int out_size, void* d_ws, size_t ws_size,
                              hipStream_t stream) {
    const float* x   = (const float*)d_in[0];
    const int*   ei  = (const int*)d_in[1];     // [2,E]: src row then dst row
    const float* nrm = (const float*)d_in[2];
    const float* W1  = (const float*)d_in[3];
    const float* b1  = (const float*)d_in[4];
    const float* g   = (const float*)d_in[5];
    const float* be  = (const float*)d_in[6];
    const float* mu  = (const float*)d_in[7];
    const float* var = (const float*)d_in[8];
    const float* W2  = (const float*)d_in[9];
    const float* b2  = (const float*)d_in[10];
    const float* pw  = (const float*)d_in[11];
    const float* pb  = (const float*)d_in[12];
    float* out = (float*)d_out;

    int N = in_sizes[0] / F;
    int E = in_sizes[2];

    char* w = (char*)d_ws;
    auto alloc = [&](size_t bytes) {
        void* p = (void*)w;
        w += ((bytes + 255) / 256) * 256;
        return p;
    };
    int*   rp     = (int*)alloc((size_t)(N + 1) * 4);
    int*   cursor = (int*)alloc((size_t)(N + 1) * 4);
    int*   bsum   = (int*)alloc(256 * 4);
    int2*  ep     = (int2*)alloc((size_t)E * 8);
    float* bufA   = (float*)alloc((size_t)N * C * 4);
    float* bufB   = (float*)alloc((size_t)N * C * 4);

    hipMemsetAsync(cursor, 0, (size_t)(N + 1) * 4, stream);

    k_count<<<(E + 255) / 256, 256, 0, stream>>>(ei + E, E, cursor);

    int n1 = N + 1;
    int NB = (n1 + 4095) / 4096;
    k_scan1<<<NB, 256, 0, stream>>>(cursor, n1, bsum);
    k_scan2<<<1, 64, 0, stream>>>(bsum, NB);
    k_scan3<<<NB, 256, 0, stream>>>(cursor, n1, bsum, rp);

    hipMemsetAsync(cursor, 0, (size_t)(N + 1) * 4, stream);
    k_fill<<<(E + 255) / 256, 256, 0, stream>>>(ei, ei + E, nrm, E, rp, cursor, ep);

    k_mlp<<<(N + TM - 1) / TM, 256, 0, stream>>>(x, W1, b1, g, be, mu, var, W2, b2,
                                                 pw, pb, bufA, out, N);

    int nodeBlocks = (N + 31) / 32;
    float* cur = bufA;
    float* nxt = bufB;
    for (int k = 0; k < KHOPS; k++) {
        k_hop<<<nodeBlocks, 320, 0, stream>>>((const float4*)cur, (float4*)nxt, (float4*)out,
                                              rp, ep, pw, pb, N);
        float* tmp = cur; cur = nxt; nxt = tmp;
    }

    k_lsm<<<nodeBlocks, 320, 0, stream>>>((float4*)out, N);
}

// Round 3
// 1136.285 us; speedup vs baseline: 1.8948x; 1.0073x over previous
//
#include <hip/hip_runtime.h>
#include <hip/hip_bf16.h>
#include <math.h>

#define F 128
#define H 256
#define C 40
#define KHOPS 10
#define TM 64
#define HK 64

// ---------------- CSR build ----------------
__global__ void k_count(const int* __restrict__ dst, int E, int* __restrict__ cnt) {
    int e = blockIdx.x * 256 + threadIdx.x;
    if (e < E) atomicAdd(&cnt[dst[e]], 1);
}

__global__ void k_scan1(const int* __restrict__ cnt, int n, int* __restrict__ bsum) {
    __shared__ int sh[256];
    int t = threadIdx.x;
    int base = blockIdx.x * 4096 + t * 16;
    int s = 0;
    for (int i = 0; i < 16; i++) { int idx = base + i; if (idx < n) s += cnt[idx]; }
    sh[t] = s; __syncthreads();
    for (int o = 128; o > 0; o >>= 1) {
        if (t < o) sh[t] += sh[t + o];
        __syncthreads();
    }
    if (t == 0) bsum[blockIdx.x] = sh[0];
}

__global__ void k_scan2(int* __restrict__ bsum, int nb) {
    if (threadIdx.x == 0) {
        int acc = 0;
        for (int i = 0; i < nb; i++) { int v = bsum[i]; bsum[i] = acc; acc += v; }
    }
}

__global__ void k_scan3(const int* __restrict__ cnt, int n, const int* __restrict__ bsum,
                        int* __restrict__ rp) {
    __shared__ int sh[256];
    int t = threadIdx.x;
    int base = blockIdx.x * 4096 + t * 16;
    int local[16]; int s = 0;
    for (int i = 0; i < 16; i++) {
        int idx = base + i;
        int v = (idx < n) ? cnt[idx] : 0;
        local[i] = v; s += v;
    }
    sh[t] = s; __syncthreads();
    for (int o = 1; o < 256; o <<= 1) {
        int v = (t >= o) ? sh[t - o] : 0;
        __syncthreads();
        sh[t] += v;
        __syncthreads();
    }
    int excl = (t == 0) ? 0 : sh[t - 1];
    int run = bsum[blockIdx.x] + excl;
    for (int i = 0; i < 16; i++) {
        int idx = base + i;
        if (idx < n) { rp[idx] = run; run += local[i]; }
    }
}

__global__ void k_fill(const int* __restrict__ src, const int* __restrict__ dst,
                       const float* __restrict__ nrm, int E, const int* __restrict__ rp,
                       int* __restrict__ cur, int2* __restrict__ ep) {
    int e = blockIdx.x * 256 + threadIdx.x;
    if (e < E) {
        int d = dst[e];
        int p = rp[d] + atomicAdd(&cur[d], 1);
        ep[p] = make_int2(src[e], __float_as_int(nrm[e]));
    }
}

// ------- fused MLP: Linear(128->256)+BN+ReLU+Linear(256->40) + retain-combine hop0 -------
__launch_bounds__(256, 2)
__global__ void k_mlp(const float* __restrict__ x, const float* __restrict__ W1,
                      const float* __restrict__ b1, const float* __restrict__ g,
                      const float* __restrict__ be, const float* __restrict__ mu,
                      const float* __restrict__ var, const float* __restrict__ W2,
                      const float* __restrict__ b2, const float* __restrict__ pw,
                      const float* __restrict__ pb,
                      float* __restrict__ h, float* __restrict__ oacc, int N) {
    __shared__ float xs[TM][132];   // [node][f]; row offset 132w: 16*132%32==0, 1*132%32==4
    __shared__ float h1s[TM][68];   // [node][hh]
    __shared__ float w2s[C][68];    // [c][hh] transposed
    __shared__ float asc[HK], dsc[HK];
    __shared__ float redc[256];
    __shared__ float sigv[TM];

    int t = threadIdx.x;
    int n0 = blockIdx.x * TM;

    // stage x tile (coalesced global, natural LDS layout)
    for (int k = 0; k < 8; k++) {
        int idx = k * 256 + t;          // over 2048 float4
        int node = idx >> 5, f4 = idx & 31;
        int n = n0 + node;
        float4 v = (n < N) ? ((const float4*)x)[(size_t)n * (F / 4) + f4]
                           : make_float4(0.f, 0.f, 0.f, 0.f);
        *((float4*)&xs[node][f4 * 4]) = v;
    }

    float acc2[10];
    {
        int cg = t & 3;
        #pragma unroll
        for (int j = 0; j < 10; j++) acc2[j] = b2[cg * 10 + j];
    }

    // stage-1 tiling: thread (tn,th) handles nodes {tn+16*i} x h {th*4+j}
    // row = tn+16*i keeps bank offset == 4*tn for all i  ->  2-way max (free)
    int tn = t & 15, th = t >> 4;
    const float4* W1g = (const float4*)W1;   // [F][H/4]

    for (int h0 = 0; h0 < H; h0 += HK) {
        // load W2 chunk transposed
        for (int k = 0; k < 10; k++) {
            int idx = k * 256 + t;      // over 2560
            int hh = idx / 40, c = idx % 40;
            w2s[c][hh] = W2[(size_t)(h0 + hh) * C + c];
        }
        // fused BN scale/shift (includes b1)
        if (t < HK) {
            int hg = h0 + t;
            float a = g[hg] * rsqrtf(var[hg] + 1e-5f);
            asc[t] = a;
            dsc[t] = (b1[hg] - mu[hg]) * a + be[hg];
        }
        __syncthreads();

        // stage 1: x @ W1 chunk (W1 from global: 16-lane broadcast b128, L1/L2-hot)
        float acc[4][4];
        #pragma unroll
        for (int i = 0; i < 4; i++)
            #pragma unroll
            for (int j = 0; j < 4; j++) acc[i][j] = 0.f;

        #pragma unroll 4
        for (int f0 = 0; f0 < F; f0 += 4) {
            float4 wv[4];
            #pragma unroll
            for (int q = 0; q < 4; q++)
                wv[q] = W1g[(size_t)(f0 + q) * (H / 4) + (h0 >> 2) + th];
            float4 xv[4];
            #pragma unroll
            for (int i = 0; i < 4; i++)
                xv[i] = *((const float4*)&xs[tn + 16 * i][f0]);
            #pragma unroll
            for (int i = 0; i < 4; i++) {
                float xa[4] = {xv[i].x, xv[i].y, xv[i].z, xv[i].w};
                #pragma unroll
                for (int q = 0; q < 4; q++) {
                    float wa[4] = {wv[q].x, wv[q].y, wv[q].z, wv[q].w};
                    #pragma unroll
                    for (int j = 0; j < 4; j++) acc[i][j] += xa[q] * wa[j];
                }
            }
        }
        // BN + ReLU -> h1s
        #pragma unroll
        for (int i = 0; i < 4; i++) {
            float4 o;
            float* po = (float*)&o;
            #pragma unroll
            for (int j = 0; j < 4; j++) {
                int hh = th * 4 + j;
                float v = acc[i][j] * asc[hh] + dsc[hh];
                po[j] = v > 0.f ? v : 0.f;
            }
            *((float4*)&h1s[tn + 16 * i][th * 4]) = o;
        }
        __syncthreads();

        // stage 2: h1 chunk @ W2 chunk
        int n_loc = t >> 2, cg = t & 3;
        #pragma unroll 4
        for (int hh = 0; hh < HK; hh += 4) {
            float4 hv = *((const float4*)&h1s[n_loc][hh]);
            #pragma unroll
            for (int j = 0; j < 10; j++) {
                float4 w4 = *((const float4*)&w2s[cg * 10 + j][hh]);
                acc2[j] += hv.x * w4.x + hv.y * w4.y + hv.z * w4.z + hv.w * w4.w;
            }
        }
        __syncthreads();
    }

    // epilogue: write h, fused snapshot-0 retain combine (out = sigmoid(h.pw+pb)*h)
    int n_loc = t >> 2, cg = t & 3;
    int n = n0 + n_loc;
    float part = 0.f;
    #pragma unroll
    for (int j = 0; j < 10; j++) part += acc2[j] * pw[cg * 10 + j];
    redc[t] = part;
    __syncthreads();
    if (cg == 0) {
        float s = redc[n_loc * 4] + redc[n_loc * 4 + 1] + redc[n_loc * 4 + 2] + redc[n_loc * 4 + 3];
        sigv[n_loc] = 1.f / (1.f + expf(-(s + pb[0])));
    }
    __syncthreads();
    if (n < N) {
        float sg = sigv[n_loc];
        #pragma unroll
        for (int j = 0; j < 10; j++) {
            h[(size_t)n * C + cg * 10 + j] = acc2[j];
            oacc[(size_t)n * C + cg * 10 + j] = sg * acc2[j];   // first contribution: store
        }
    }
}

// ---------------- one propagation hop, fused with retain-combine ----------------
// 320 threads: 64 nodes/block, 5 lanes/node, 2 float4 per lane.
__global__ void k_hop(const float4* __restrict__ cur4, float4* __restrict__ nxt4,
                      float4* __restrict__ oacc4, const int* __restrict__ rp,
                      const int2* __restrict__ ep,
                      const float* __restrict__ pw, const float* __restrict__ pb, int N) {
    __shared__ float red[320];
    __shared__ float sig[64];
    int t = threadIdx.x;
    int nl = t / 5, p = t % 5;
    int n = blockIdx.x * 64 + nl;
    int c0 = 2 * p;
    float4 a0 = make_float4(0.f, 0.f, 0.f, 0.f);
    float4 a1 = make_float4(0.f, 0.f, 0.f, 0.f);
    if (n < N) {
        int b = rp[n], e = rp[n + 1];
        int j = b;
        for (; j + 4 <= e; j += 4) {
            int2 e0 = ep[j], e1 = ep[j + 1], e2 = ep[j + 2], e3 = ep[j + 3];
            const float4* r0 = cur4 + (size_t)e0.x * 10 + c0;
            const float4* r1 = cur4 + (size_t)e1.x * 10 + c0;
            const float4* r2 = cur4 + (size_t)e2.x * 10 + c0;
            const float4* r3 = cur4 + (size_t)e3.x * 10 + c0;
            float4 v00 = r0[0], v01 = r0[1];
            float4 v10 = r1[0], v11 = r1[1];
            float4 v20 = r2[0], v21 = r2[1];
            float4 v30 = r3[0], v31 = r3[1];
            float w0 = __int_as_float(e0.y), w1 = __int_as_float(e1.y);
            float w2 = __int_as_float(e2.y), w3 = __int_as_float(e3.y);
            a0.x += w0 * v00.x; a0.y += w0 * v00.y; a0.z += w0 * v00.z; a0.w += w0 * v00.w;
            a1.x += w0 * v01.x; a1.y += w0 * v01.y; a1.z += w0 * v01.z; a1.w += w0 * v01.w;
            a0.x += w1 * v10.x; a0.y += w1 * v10.y; a0.z += w1 * v10.z; a0.w += w1 * v10.w;
            a1.x += w1 * v11.x; a1.y += w1 * v11.y; a1.z += w1 * v11.z; a1.w += w1 * v11.w;
            a0.x += w2 * v20.x; a0.y += w2 * v20.y; a0.z += w2 * v20.z; a0.w += w2 * v20.w;
            a1.x += w2 * v21.x; a1.y += w2 * v21.y; a1.z += w2 * v21.z; a1.w += w2 * v21.w;
            a0.x += w3 * v30.x; a0.y += w3 * v30.y; a0.z += w3 * v30.z; a0.w += w3 * v30.w;
            a1.x += w3 * v31.x; a1.y += w3 * v31.y; a1.z += w3 * v31.z; a1.w += w3 * v31.w;
        }
        if (j + 2 <= e) {
            int2 e0 = ep[j], e1 = ep[j + 1];
            const float4* r0 = cur4 + (size_t)e0.x * 10 + c0;
            const float4* r1 = cur4 + (size_t)e1.x * 10 + c0;
            float4 v00 = r0[0], v01 = r0[1];
            float4 v10 = r1[0], v11 = r1[1];
            float w0 = __int_as_float(e0.y), w1 = __int_as_float(e1.y);
            a0.x += w0 * v00.x; a0.y += w0 * v00.y; a0.z += w0 * v00.z; a0.w += w0 * v00.w;
            a1.x += w0 * v01.x; a1.y += w0 * v01.y; a1.z += w0 * v01.z; a1.w += w0 * v01.w;
            a0.x += w1 * v10.x; a0.y += w1 * v10.y; a0.z += w1 * v10.z; a0.w += w1 * v10.w;
            a1.x += w1 * v11.x; a1.y += w1 * v11.y; a1.z += w1 * v11.z; a1.w += w1 * v11.w;
            j += 2;
        }
        if (j < e) {
            int2 e0 = ep[j];
            const float4* r0 = cur4 + (size_t)e0.x * 10 + c0;
            float4 v00 = r0[0], v01 = r0[1];
            float w0 = __int_as_float(e0.y);
            a0.x += w0 * v00.x; a0.y += w0 * v00.y; a0.z += w0 * v00.z; a0.w += w0 * v00.w;
            a1.x += w0 * v01.x; a1.y += w0 * v01.y; a1.z += w0 * v01.z; a1.w += w0 * v01.w;
        }
        nxt4[(size_t)n * 10 + c0] = a0;
        nxt4[(size_t)n * 10 + c0 + 1] = a1;
    }
    // retain-combine
    float4 pw0 = ((const float4*)pw)[c0];
    float4 pw1 = ((const float4*)pw)[c0 + 1];
    red[t] = a0.x * pw0.x + a0.y * pw0.y + a0.z * pw0.z + a0.w * pw0.w
           + a1.x * pw1.x + a1.y * pw1.y + a1.z * pw1.z + a1.w * pw1.w;
    __syncthreads();
    if (p == 0) {
        float s = red[t] + red[t + 1] + red[t + 2] + red[t + 3] + red[t + 4];
        sig[nl] = 1.f / (1.f + expf(-(s + pb[0])));
    }
    __syncthreads();
    if (n < N) {
        float sg = sig[nl];
        size_t o = (size_t)n * 10 + c0;
        float4 v0 = oacc4[o], v1 = oacc4[o + 1];
        v0.x += sg * a0.x; v0.y += sg * a0.y; v0.z += sg * a0.z; v0.w += sg * a0.w;
        v1.x += sg * a1.x; v1.y += sg * a1.y; v1.z += sg * a1.z; v1.w += sg * a1.w;
        oacc4[o] = v0;
        oacc4[o + 1] = v1;
    }
}

// ---------------- in-place log_softmax over C (float4) ----------------
__global__ void k_lsm(float4* __restrict__ io, int N) {
    __shared__ float red[320];
    __shared__ float statm[32];
    __shared__ float stats[32];
    int t = threadIdx.x;
    int nl = t / 10, c4 = t % 10;
    int n = blockIdx.x * 32 + nl;
    bool ok = n < N;
    float4 v = ok ? io[(size_t)n * 10 + c4] : make_float4(-1e30f, -1e30f, -1e30f, -1e30f);
    red[t] = fmaxf(fmaxf(v.x, v.y), fmaxf(v.z, v.w));
    __syncthreads();
    if (c4 == 0) {
        float m = -1e30f;
        #pragma unroll
        for (int q = 0; q < 10; q++) m = fmaxf(m, red[nl * 10 + q]);
        statm[nl] = m;
    }
    __syncthreads();
    float m = statm[nl];
    float e0 = expf(v.x - m), e1 = expf(v.y - m), e2 = expf(v.z - m), e3 = expf(v.w - m);
    red[t] = e0 + e1 + e2 + e3;
    __syncthreads();
    if (c4 == 0) {
        float s = 0.f;
        #pragma unroll
        for (int q = 0; q < 10; q++) s += red[nl * 10 + q];
        stats[nl] = logf(s);
    }
    __syncthreads();
    if (ok) {
        float ls = stats[nl];
        io[(size_t)n * 10 + c4] = make_float4(v.x - m - ls, v.y - m - ls, v.z - m - ls, v.w - m - ls);
    }
}

extern "C" void kernel_launch(void* const* d_in, const int* in_sizes, int n_in,
                              void* d_out, int out_size, void* d_ws, size_t ws_size,
                              hipStream_t stream) {
    const float* x   = (const float*)d_in[0];
    const int*   ei  = (const int*)d_in[1];     // [2,E]: src row then dst row
    const float* nrm = (const float*)d_in[2];
    const float* W1  = (const float*)d_in[3];
    const float* b1  = (const float*)d_in[4];
    const float* g   = (const float*)d_in[5];
    const float* be  = (const float*)d_in[6];
    const float* mu  = (const float*)d_in[7];
    const float* var = (const float*)d_in[8];
    const float* W2  = (const float*)d_in[9];
    const float* b2  = (const float*)d_in[10];
    const float* pw  = (const float*)d_in[11];
    const float* pb  = (const float*)d_in[12];
    float* out = (float*)d_out;

    int N = in_sizes[0] / F;
    int E = in_sizes[2];

    char* w = (char*)d_ws;
    auto alloc = [&](size_t bytes) {
        void* p = (void*)w;
        w += ((bytes + 255) / 256) * 256;
        return p;
    };
    int*   rp     = (int*)alloc((size_t)(N + 1) * 4);
    int*   cursor = (int*)alloc((size_t)(N + 1) * 4);
    int*   bsum   = (int*)alloc(256 * 4);
    int2*  ep     = (int2*)alloc((size_t)E * 8);
    float* bufA   = (float*)alloc((size_t)N * C * 4);
    float* bufB   = (float*)alloc((size_t)N * C * 4);

    hipMemsetAsync(cursor, 0, (size_t)(N + 1) * 4, stream);

    k_count<<<(E + 255) / 256, 256, 0, stream>>>(ei + E, E, cursor);

    int n1 = N + 1;
    int NB = (n1 + 4095) / 4096;
    k_scan1<<<NB, 256, 0, stream>>>(cursor, n1, bsum);
    k_scan2<<<1, 64, 0, stream>>>(bsum, NB);
    k_scan3<<<NB, 256, 0, stream>>>(cursor, n1, bsum, rp);

    hipMemsetAsync(cursor, 0, (size_t)(N + 1) * 4, stream);
    k_fill<<<(E + 255) / 256, 256, 0, stream>>>(ei, ei + E, nrm, E, rp, cursor, ep);

    k_mlp<<<(N + TM - 1) / TM, 256, 0, stream>>>(x, W1, b1, g, be, mu, var, W2, b2,
                                                 pw, pb, bufA, out, N);

    int nodeBlocks64 = (N + 63) / 64;
    float* cur = bufA;
    float* nxt = bufB;
    for (int k = 0; k < KHOPS; k++) {
        k_hop<<<nodeBlocks64, 320, 0, stream>>>((const float4*)cur, (float4*)nxt, (float4*)out,
                                                rp, ep, pw, pb, N);
        float* tmp = cur; cur = nxt; nxt = tmp;
    }

    int nodeBlocks32 = (N + 31) / 32;
    k_lsm<<<nodeBlocks32, 320, 0, stream>>>((float4*)out, N);
}